// Round 1
// baseline (5004.540 us; speedup 1.0000x reference)
//
#include <hip/hip_runtime.h>

typedef unsigned int uint32;
typedef unsigned short u16;
typedef __attribute__((ext_vector_type(8))) short bf8;   // 8 x bf16 (4 VGPRs)
typedef __attribute__((ext_vector_type(4))) float f4;    // 4 x f32 accum

#define DEV static __device__ __forceinline__

DEV f4 MFMA(bf8 a, bf8 b, f4 c) {
  return __builtin_amdgcn_mfma_f32_16x16x32_bf16(a, b, c, 0, 0, 0);
}
DEV u16 f2bf(float f) {
  uint32 u = __float_as_uint(f);
  return (u16)((u + 0x7FFFu + ((u >> 16) & 1u)) >> 16);
}
DEV float bf2f(u16 h) { return __uint_as_float(((uint32)h) << 16); }
DEV float bfLO(uint32 u) { return __uint_as_float(u << 16); }
DEV float bfHI(uint32 u) { return __uint_as_float(u & 0xFFFF0000u); }
DEV float sigmoid_(float x) { return 1.f / (1.f + __expf(-x)); }
DEV float tanh_(float x) {
  float cx = fminf(fmaxf(x, -15.f), 15.f);
  float e = __expf(2.f * cx);
  return (e - 1.f) / (e + 1.f);
}

DEV void arrive(int* f) {
  __hip_atomic_fetch_add(f, 1, __ATOMIC_RELEASE, __HIP_MEMORY_SCOPE_AGENT);
}
DEV void waitge(int* f, int tgt) {
  for (int i = 0; i < (1 << 19); ++i) {
    if (__hip_atomic_load(f, __ATOMIC_ACQUIRE, __HIP_MEMORY_SCOPE_AGENT) >= tgt) return;
    __builtin_amdgcn_s_sleep(1);
  }
}

namespace L {
// sizes: B=32,S=60,T=59,V=50000,E=300(pad320),H=512,3H=1536
constexpr size_t o_flags  = 0;          // 1024 int
constexpr size_t o_rowsum = 4096;       // 1920 f32
constexpr size_t o_bcomb  = 11776;      // 1536 f32
constexpr size_t o_gistat = 17920;      // 32x1536 f32
constexpr size_t o_xbuf   = 214528;     // 2x32x1024 bf16  (attn | h)
constexpr size_t o_henc   = 345600;     // 2x32x512 bf16
constexpr size_t o_haff   = 411136;     // 2x32x512 bf16
constexpr size_t o_cat    = 476672;     // 32x1024 bf16 (state_enc | state_aff)
constexpr size_t o_Kbuf   = 542208;     // 1920x512 bf16 (row = s*32+b)
constexpr size_t o_KA     = 2508288;    // 1920x512 bf16
constexpr size_t o_embP   = 4474368;    // 1920x320 bf16
constexpr size_t o_embA   = 5703168;    // 1920x320 bf16
constexpr size_t o_embD   = 6931968;    // 1888x320 bf16
constexpr size_t o_encWi  = 8140288;    // 1536x320 bf16
constexpr size_t o_affWi  = 9123328;    // 1536x320 bf16
constexpr size_t o_Whe    = 10106368;   // 1536x512 bf16
constexpr size_t o_Wha    = 11679232;   // 1536x512 bf16
constexpr size_t o_decWi  = 13252096;   // 1536x512 bf16
constexpr size_t o_WlT    = 14824960;   // 1328x512 bf16
constexpr size_t o_Wa     = 16184832;   // 512x512 bf16
constexpr size_t o_Wp     = 16709120;   // 512x1024 bf16
constexpr size_t o_wq     = 17757696;   // 32768 uint4 (packed Wc^T pairs)
constexpr size_t o_Wcomb  = 18281984;   // 1536x1328 f32
constexpr size_t o_WdE    = 26441216;   // 1536x320 bf16
constexpr size_t o_WdA    = 27424256;   // 1536x512 bf16
constexpr size_t o_Wd2    = 28997120;   // 1536x1024 bf16 (Wcomb_attn | dec_Wh)
constexpr size_t o_giE    = 32142848;   // 1920x1536 f32
constexpr size_t o_giA    = 43939328;   // 1920x1536 f32
constexpr size_t o_giD    = 55735808;   // 1888x1536 f32
constexpr size_t o_outsB  = 67335680;   // 1920x1024 bf16 (row = b*59+t : h|attn)
constexpr size_t o_WvB    = 71267840;   // 50176x1024 bf16 (optional)
constexpr size_t WS_FULL  = 174028288;
constexpr size_t WOFF = 94400000;       // weights output offset (floats)
}

// ---------------- prep: embedding gathers -> bf16, padded K=320 ----------------
__global__ __launch_bounds__(256) void kp_gather(
    const int* __restrict__ posts, const int* __restrict__ resp,
    const float* __restrict__ emb, const float* __restrict__ aemb, char* ws)
{
  using namespace L;
  const int gid = blockIdx.x * 256 + threadIdx.x;
  const int r = gid / 320, e = gid - r * 320;
  u16* embP = (u16*)(ws + o_embP);
  u16* embA = (u16*)(ws + o_embA);
  u16* embD = (u16*)(ws + o_embD);
  if (r < 1920) {
    const int b = r & 31, s = r >> 5;
    const int tok = posts[b * 60 + s];
    embP[r * 320 + e] = f2bf(e < 300 ? emb[(size_t)tok * 300 + e] : 0.f);
    embA[r * 320 + e] = f2bf(e < 300 ? aemb[(size_t)tok * 300 + e] : 0.f);
  } else if (r < 3808) {
    const int r2 = r - 1920;
    const int b = r2 & 31, t = r2 >> 5;
    const int tok = resp[b * 60 + t];
    embD[r2 * 320 + e] = f2bf(e < 300 ? emb[(size_t)tok * 300 + e] : 0.f);
  }
}

// ---------------- prep: weight conversions / transposes / zeroing ----------------
__global__ __launch_bounds__(256) void kp_wconv(
    const float* __restrict__ encWi, const float* __restrict__ affWi,
    const float* __restrict__ encWh, const float* __restrict__ affWh,
    const float* __restrict__ dWi, const float* __restrict__ Wl,
    const float* __restrict__ Wa, const float* __restrict__ Wp,
    const float* __restrict__ Wc, char* ws)
{
  using namespace L;
  long gid = (long)blockIdx.x * 256 + threadIdx.x;
  if (gid < 983040) {  // enc_Wi / aff_Wi -> [1536][320] bf16 (pad)
    const int g = gid >= 491520;
    const long u = gid - (g ? 491520 : 0);
    const int n = (int)(u / 320), e = (int)(u - (long)n * 320);
    const float* src = g ? affWi : encWi;
    u16* dst = (u16*)(ws + (g ? o_affWi : o_encWi));
    dst[u] = f2bf(e < 300 ? src[(size_t)n * 300 + e] : 0.f);
    return;
  }
  gid -= 983040;
  if (gid < 2359296) {  // enc_Wh / aff_Wh / dec_Wi -> bf16 direct
    const int g = (int)(gid / 786432);
    const long u = gid - (long)g * 786432;
    const float* src = g == 0 ? encWh : (g == 1 ? affWh : dWi);
    u16* dst = (u16*)(ws + (g == 0 ? o_Whe : (g == 1 ? o_Wha : o_decWi)));
    dst[u] = f2bf(src[u]);
    return;
  }
  gid -= 2359296;
  if (gid < 679936) {  // Wl^T -> [1328][512] bf16 (pad rows)
    const int j = (int)(gid >> 9), k = (int)(gid & 511);
    ((u16*)(ws + o_WlT))[gid] = f2bf(j < 1324 ? Wl[(size_t)k * 1324 + j] : 0.f);
    return;
  }
  gid -= 679936;
  if (gid < 262144) { ((u16*)(ws + o_Wa))[gid] = f2bf(Wa[gid]); return; }
  gid -= 262144;
  if (gid < 524288) { ((u16*)(ws + o_Wp))[gid] = f2bf(Wp[gid]); return; }
  gid -= 524288;
  if (gid < 131072) {  // packed Wc^T pairs: u32 idx = (g4*512+j)*4+q ; d0 = g4*8+q*2
    const int q = (int)(gid & 3), j = (int)((gid >> 2) & 511), g4 = (int)(gid >> 11);
    const int d0 = g4 * 8 + q * 2;
    const uint32 lo = f2bf(Wc[(size_t)j * 512 + d0]);
    const uint32 hi = f2bf(Wc[(size_t)j * 512 + d0 + 1]);
    ((uint32*)(ws + o_wq))[gid] = lo | (hi << 16);
    return;
  }
  gid -= 131072;
  if (gid < 2944) {  // zero flags + rowsum
    if (gid < 1024) ((uint32*)(ws + o_flags))[gid] = 0;
    else ((uint32*)(ws + o_rowsum))[gid - 1024] = 0;
    return;
  }
  gid -= 2944;
  if (gid < 49152) {  // zero: outsB pad rows, henc, haff (u32 words)
    if (gid < 16384) ((uint32*)(ws + o_outsB + (size_t)1888 * 1024 * 2))[gid] = 0;
    else if (gid < 32768) ((uint32*)(ws + o_henc))[gid - 16384] = 0;
    else ((uint32*)(ws + o_haff))[gid - 32768] = 0;
  }
}

// ---------------- prep: bcomb = dec_Wi @ bl + dec_bi ----------------
__global__ __launch_bounds__(256) void kp_bcomb(
    const float* __restrict__ dWi, const float* __restrict__ bl,
    const float* __restrict__ dbi, char* ws)
{
  const int i = blockIdx.x * 256 + threadIdx.x;
  if (i >= 1536) return;
  float a = dbi[i];
  for (int k = 0; k < 512; ++k) a += dWi[(size_t)i * 512 + k] * bl[k];
  ((float*)(ws + L::o_bcomb))[i] = a;
}

// ---------------- prep: Wv -> bf16 (padded rows) ----------------
__global__ __launch_bounds__(256) void kp_wv(const float* __restrict__ Wv, char* ws)
{
  const long gid = (long)blockIdx.x * 256 + threadIdx.x;
  const int r = (int)(gid >> 8), q = (int)(gid & 255);
  u16* WvB = (u16*)(ws + L::o_WvB);
  uint2 o;
  if (r < 50000) {
    const float4 f = *(const float4*)(Wv + (size_t)r * 1024 + q * 4);
    o.x = (uint32)f2bf(f.x) | ((uint32)f2bf(f.y) << 16);
    o.y = (uint32)f2bf(f.z) | ((uint32)f2bf(f.w) << 16);
  } else { o.x = 0u; o.y = 0u; }
  *(uint2*)(WvB + (size_t)r * 1024 + q * 4) = o;
}

// ---------------- prep: split Wcomb into bf16 pieces ----------------
__global__ __launch_bounds__(256) void kp_pack2(
    const float* __restrict__ Wcomb, const float* __restrict__ dWh, char* ws)
{
  using namespace L;
  long gid = (long)blockIdx.x * 256 + threadIdx.x;
  if (gid < 491520) {  // Wd_emb [1536][320] <- Wcomb[:,0:300]
    const int n = (int)(gid / 320), e = (int)(gid - (long)n * 320);
    ((u16*)(ws + o_WdE))[gid] = f2bf(e < 300 ? Wcomb[(size_t)n * 1328 + e] : 0.f);
    return;
  }
  gid -= 491520;
  if (gid < 786432) {  // Wd_aff [1536][512] <- Wcomb[:,300:812]
    const int n = (int)(gid >> 9), k = (int)(gid & 511);
    ((u16*)(ws + o_WdA))[gid] = f2bf(Wcomb[(size_t)n * 1328 + 300 + k]);
    return;
  }
  gid -= 786432;
  if (gid < 1572864) {  // Wd2 [1536][1024] = [Wcomb[:,812:1324] | dec_Wh]
    const int n = (int)(gid >> 10), k = (int)(gid & 1023);
    const float v = (k < 512) ? Wcomb[(size_t)n * 1328 + 812 + k]
                              : dWh[(size_t)n * 512 + (k - 512)];
    ((u16*)(ws + o_Wd2))[gid] = f2bf(v);
  }
}

// ---------------- generic MFMA GEMM: C[M][N] = A[M][Kp] * B[N][Kp]^T (+bias) ----------------
__global__ __launch_bounds__(256) void k_gemm_nt(
    const u16* __restrict__ A, const u16* __restrict__ Bm,
    float* __restrict__ C, const float* __restrict__ bias,
    const int M, const int N, const int Kp)
{
  const int mt = blockIdx.x, cb = blockIdx.y;
  const int w = threadIdx.x >> 6, lane = threadIdx.x & 63;
  const int l15 = lane & 15, lhi = lane >> 4;
  const u16* arow = A + (size_t)(mt * 16 + l15) * Kp + lhi * 8;
  const int c0 = cb * 256 + w * 64;
  f4 acc[4];
#pragma unroll
  for (int nn = 0; nn < 4; ++nn) acc[nn] = (f4){0.f, 0.f, 0.f, 0.f};
  for (int k = 0; k < Kp; k += 32) {
    const bf8 a = *(const bf8*)(arow + k);
#pragma unroll
    for (int nn = 0; nn < 4; ++nn) {
      const int cs = c0 + nn * 16;
      if (cs < N) {
        const bf8 b = *(const bf8*)(Bm + (size_t)(cs + l15) * Kp + k + lhi * 8);
        acc[nn] = MFMA(a, b, acc[nn]);
      }
    }
  }
#pragma unroll
  for (int nn = 0; nn < 4; ++nn) {
    const int cs = c0 + nn * 16;
    if (cs >= N) continue;
    const int c = cs + l15;
    const float bb = bias ? bias[c] : 0.f;
#pragma unroll
    for (int j = 0; j < 4; ++j) {
      const int r = mt * 16 + lhi * 4 + j;
      C[(size_t)r * N + c] = acc[nn][j] + bb;
    }
  }
}

// ---------------- persistent recurrent kernel ----------------
__global__ __launch_bounds__(256) void k_persist(
    char* __restrict__ ws, float* __restrict__ out,
    const float* __restrict__ bp, const float* __restrict__ enc_bh,
    const float* __restrict__ aff_bh, const float* __restrict__ dec_bh,
    const float* __restrict__ bc)
{
  using namespace L;
  const int tid = threadIdx.x;
  const int blk = blockIdx.x;
  const int wave = tid >> 6, lane = tid & 63;
  const int l15 = lane & 15, lhi = lane >> 4;
  int* flags = (int*)(ws + o_flags);

  __shared__ float hsm[512];
  __shared__ float ctxs[512];
  __shared__ float scb[64];
  __shared__ float wsb[64];

  u16* xb = (u16*)(ws + o_xbuf);
  u16* outs = (u16*)(ws + o_outsB);
  u16* cat = (u16*)(ws + o_cat);
  u16* Kb = (u16*)(ws + o_Kbuf);

  // ============ encoder: blocks 0-15 (word GRU), 16-31 (affect GRU) ============
  if (blk < 32) {
    const int g = blk >> 4;
    const u16* Wh = (const u16*)(ws + (g ? o_Wha : o_Whe));
    const float* gi = (const float*)(ws + (g ? o_giA : o_giE));
    const float* bh = g ? aff_bh : enc_bh;
    u16* hbuf = (u16*)(ws + (g ? o_haff : o_henc));
    const int wid = (blk & 15) * 4 + wave;
    const int mt = wid >> 5, ct = wid & 31;
    const int c = ct * 16 + l15;
    const u16* wr0 = Wh + (size_t)c * 512 + lhi * 8;
    const u16* wr1 = Wh + (size_t)(512 + c) * 512 + lhi * 8;
    const u16* wr2 = Wh + (size_t)(1024 + c) * 512 + lhi * 8;
    const float bhr = bh[c], bhz = bh[512 + c], bhn = bh[1024 + c];
    for (int s = 0; s < 60; ++s) {
      const u16* hin = hbuf + (s & 1) * (32 * 512);
      u16* hout = hbuf + ((s & 1) ^ 1) * (32 * 512);
      const u16* arow = hin + (mt * 16 + l15) * 512 + lhi * 8;
      f4 ar = {0.f, 0.f, 0.f, 0.f}, az = ar, an = ar;
      for (int k = 0; k < 512; k += 32) {
        const bf8 a = *(const bf8*)(arow + k);
        ar = MFMA(a, *(const bf8*)(wr0 + k), ar);
        az = MFMA(a, *(const bf8*)(wr1 + k), az);
        an = MFMA(a, *(const bf8*)(wr2 + k), an);
      }
#pragma unroll
      for (int j = 0; j < 4; ++j) {
        const int b = mt * 16 + lhi * 4 + j;
        const float* gr = gi + (size_t)(s * 32 + b) * 1536;
        const float r = sigmoid_(gr[c] + ar[j] + bhr);
        const float z = sigmoid_(gr[512 + c] + az[j] + bhz);
        const float n = tanh_(gr[1024 + c] + r * (an[j] + bhn));
        const float hold = bf2f(hin[b * 512 + c]);
        const u16 hb = f2bf((1.f - z) * n + z * hold);
        hout[b * 512 + c] = hb;
        cat[b * 1024 + g * 512 + c] = hb;
        if (g) Kb[(size_t)(s * 32 + b) * 512 + c] = hb;
      }
      __syncthreads();
      if (tid == 0) { arrive(&flags[g * 60 + s]); waitge(&flags[g * 60 + s], 16); }
      __syncthreads();
    }
  }
  __syncthreads();
  if (tid == 0) { arrive(&flags[120]); waitge(&flags[120], 80); }
  __syncthreads();

  // ============ post-encoder ============
  if (blk < 16) {  // state0 = tanh(cat @ Wp^T + bp) -> xbuf[0] (attn half = 0)
    const u16* Wp_ = (const u16*)(ws + o_Wp);
    const int wid = blk * 4 + wave;
    const int mt = wid >> 5, ct = wid & 31;
    const int c = ct * 16 + l15;
    const u16* arow = cat + (mt * 16 + l15) * 1024 + lhi * 8;
    const u16* brow = Wp_ + (size_t)c * 1024 + lhi * 8;
    f4 acc = {0.f, 0.f, 0.f, 0.f};
    for (int k = 0; k < 1024; k += 32)
      acc = MFMA(*(const bf8*)(arow + k), *(const bf8*)(brow + k), acc);
    const float bpc = bp[c];
#pragma unroll
    for (int j = 0; j < 4; ++j) {
      const int b = mt * 16 + lhi * 4 + j;
      xb[b * 1024 + 512 + c] = f2bf(tanh_(acc[j] + bpc));
      xb[b * 1024 + c] = 0;
    }
  } else if (blk < 32) {  // gi_static = ctx_aff @ Wd_aff^T + bcomb
    const u16* WdA = (const u16*)(ws + o_WdA);
    const float* bco = (const float*)(ws + o_bcomb);
    float* gst = (float*)(ws + o_gistat);
    const int wid = (blk - 16) * 4 + wave;
    const int mt = wid >> 5, ctb = wid & 31;
    const u16* arow = cat + (mt * 16 + l15) * 1024 + 512 + lhi * 8;
    const int c0 = ctb * 16 + l15, c1 = c0 + 512, c2 = c0 + 1024;
    const u16* b0 = WdA + (size_t)c0 * 512 + lhi * 8;
    const u16* b1 = WdA + (size_t)c1 * 512 + lhi * 8;
    const u16* b2 = WdA + (size_t)c2 * 512 + lhi * 8;
    f4 a0 = {0.f, 0.f, 0.f, 0.f}, a1 = a0, a2 = a0;
    for (int k = 0; k < 512; k += 32) {
      const bf8 a = *(const bf8*)(arow + k);
      a0 = MFMA(a, *(const bf8*)(b0 + k), a0);
      a1 = MFMA(a, *(const bf8*)(b1 + k), a1);
      a2 = MFMA(a, *(const bf8*)(b2 + k), a2);
    }
    const float v0 = bco[c0], v1 = bco[c1], v2 = bco[c2];
#pragma unroll
    for (int j = 0; j < 4; ++j) {
      const int b = mt * 16 + lhi * 4 + j;
      gst[b * 1536 + c0] = a0[j] + v0;
      gst[b * 1536 + c1] = a1[j] + v1;
      gst[b * 1536 + c2] = a2[j] + v2;
    }
  } else {  // KA = K @ Wa^T  (folds per-step h@Wa into precompute)
    const u16* Wa_ = (const u16*)(ws + o_Wa);
    u16* KAp = (u16*)(ws + o_KA);
    const int widK = (blk - 32) * 4 + wave;
    for (int task = widK; task < 3840; task += 192) {
      const int mt = task >> 5, ct = task & 31;
      const int c = ct * 16 + l15;
      const u16* arow = Kb + (size_t)(mt * 16 + l15) * 512 + lhi * 8;
      const u16* brow = Wa_ + (size_t)c * 512 + lhi * 8;
      f4 acc = {0.f, 0.f, 0.f, 0.f};
      for (int k = 0; k < 512; k += 32)
        acc = MFMA(*(const bf8*)(arow + k), *(const bf8*)(brow + k), acc);
#pragma unroll
      for (int j = 0; j < 4; ++j)
        KAp[(size_t)(mt * 16 + lhi * 4 + j) * 512 + c] = f2bf(acc[j]);
    }
  }
  __syncthreads();
  if (tid == 0) { arrive(&flags[121]); waitge(&flags[121], 80); }
  __syncthreads();

  // ============ decoder ============
  if (blk < 16) {
    // A-role: h_t = GRU from [attn_{t-1} ; h_{t-1}] via Wd2 (K=1024), n-gate split
    const u16* Wd2 = (const u16*)(ws + o_Wd2);
    const float* gst = (const float*)(ws + o_gistat);
    const float* gD = (const float*)(ws + o_giD);
    const int wid = blk * 4 + wave;
    const int mt = wid >> 5, ct = wid & 31;
    const int c = ct * 16 + l15;
    const u16* wr = Wd2 + (size_t)c * 1024 + lhi * 8;
    const u16* wz = Wd2 + (size_t)(512 + c) * 1024 + lhi * 8;
    const u16* wn = Wd2 + (size_t)(1024 + c) * 1024 + lhi * 8;
    const float bhr = dec_bh[c], bhz = dec_bh[512 + c], bhn = dec_bh[1024 + c];
    for (int t = 0; t < 59; ++t) {
      if (t) {
        __syncthreads();
        if (tid == 0) waitge(&flags[192 + t - 1], 64);
        __syncthreads();
      }
      const u16* xin = xb + (t & 1) * (32 * 1024);
      u16* xout = xb + ((t & 1) ^ 1) * (32 * 1024);
      const u16* arow = xin + (mt * 16 + l15) * 1024 + lhi * 8;
      f4 ar = {0.f, 0.f, 0.f, 0.f}, az = ar, anx = ar, anh = ar;
      for (int k = 0; k < 512; k += 32) {
        const bf8 a = *(const bf8*)(arow + k);
        ar = MFMA(a, *(const bf8*)(wr + k), ar);
        az = MFMA(a, *(const bf8*)(wz + k), az);
        anx = MFMA(a, *(const bf8*)(wn + k), anx);
      }
      for (int k = 512; k < 1024; k += 32) {
        const bf8 a = *(const bf8*)(arow + k);
        ar = MFMA(a, *(const bf8*)(wr + k), ar);
        az = MFMA(a, *(const bf8*)(wz + k), az);
        anh = MFMA(a, *(const bf8*)(wn + k), anh);
      }
#pragma unroll
      for (int j = 0; j < 4; ++j) {
        const int b = mt * 16 + lhi * 4 + j;
        const float* g1 = gst + b * 1536;
        const float* g2 = gD + (size_t)(t * 32 + b) * 1536;
        const float r = sigmoid_(g1[c] + g2[c] + ar[j] + bhr);
        const float z = sigmoid_(g1[512 + c] + g2[512 + c] + az[j] + bhz);
        const float n = tanh_(g1[1024 + c] + g2[1024 + c] + anx[j] + r * (anh[j] + bhn));
        const float hold = bf2f(xin[b * 1024 + 512 + c]);
        const u16 hb = f2bf((1.f - z) * n + z * hold);
        xout[b * 1024 + 512 + c] = hb;
        outs[(size_t)(b * 59 + t) * 1024 + c] = hb;
      }
      __syncthreads();
      if (tid == 0) arrive(&flags[128 + t]);
    }
  } else {
    // B-role: 2 blocks per batch element: scores -> softmax -> ctx -> attn
    const int idx = blk - 16;
    const int b = idx >> 1, half = idx & 1;
    const u16* KAp = (const u16*)(ws + o_KA);
    const uint4* wq = (const uint4*)(ws + o_wq);
    for (int t = 0; t < 59; ++t) {
      if (tid == 0) waitge(&flags[128 + t], 16);
      __syncthreads();
      const u16* xcur = xb + ((t & 1) ^ 1) * (32 * 1024);
      hsm[tid] = bf2f(xcur[b * 1024 + 512 + tid]);
      hsm[tid + 256] = bf2f(xcur[b * 1024 + 512 + tid + 256]);
      __syncthreads();
      if (tid < 240) {  // scores[s] = h . KA[s,b,:]
        const int s = tid >> 2, q = tid & 3;
        const u16* kr = KAp + (size_t)(s * 32 + b) * 512 + q * 128;
        const float* hq = &hsm[q * 128];
        float acc = 0.f;
#pragma unroll 4
        for (int i = 0; i < 128; i += 4) {
          const uint2 k4 = *(const uint2*)(kr + i);
          const float4 h4 = *(const float4*)(hq + i);
          acc += h4.x * bfLO(k4.x) + h4.y * bfHI(k4.x)
               + h4.z * bfLO(k4.y) + h4.w * bfHI(k4.y);
        }
        acc += __shfl_xor(acc, 1);
        acc += __shfl_xor(acc, 2);
        if ((tid & 3) == 0) scb[s] = acc;
      }
      __syncthreads();
      if (tid < 64) {  // softmax over 60
        const float v = (tid < 60) ? scb[tid] : -1e30f;
        float m = v;
#pragma unroll
        for (int d = 1; d < 64; d <<= 1) m = fmaxf(m, __shfl_xor(m, d));
        const float e = (tid < 60) ? __expf(v - m) : 0.f;
        float sm = e;
#pragma unroll
        for (int d = 1; d < 64; d <<= 1) sm += __shfl_xor(sm, d);
        const float w = e / sm;
        if (tid < 60) {
          wsb[tid] = w;
          if (half == 0) out[WOFF + (size_t)(b * 59 + t) * 60 + tid] = w;
        }
      }
      __syncthreads();
      float c0 = 0.f, c1 = 0.f;  // ctx = sum_s w[s] * K[s,b,:]
      for (int s = 0; s < 60; ++s) {
        const float w = wsb[s];
        const u16* krow = Kb + (size_t)(s * 32 + b) * 512;
        c0 += w * bf2f(krow[tid]);
        c1 += w * bf2f(krow[tid + 256]);
      }
      ctxs[tid] = c0;
      ctxs[tid + 256] = c1;
      __syncthreads();
      const int jj = half * 256 + tid;  // attn[jj] = tanh(bc + ctx . Wc[jj,:])
      float fa = bc[jj];
#pragma unroll 2
      for (int g4 = 0; g4 < 64; ++g4) {
        const uint4 wv4 = wq[g4 * 512 + jj];
        const float4 ca = *(const float4*)&ctxs[g4 * 8];
        const float4 cb2 = *(const float4*)&ctxs[g4 * 8 + 4];
        fa += ca.x * bfLO(wv4.x) + ca.y * bfHI(wv4.x);
        fa += ca.z * bfLO(wv4.y) + ca.w * bfHI(wv4.y);
        fa += cb2.x * bfLO(wv4.z) + cb2.y * bfHI(wv4.z);
        fa += cb2.z * bfLO(wv4.w) + cb2.w * bfHI(wv4.w);
      }
      const u16 ab = f2bf(tanh_(fa));
      u16* xout = xb + ((t & 1) ^ 1) * (32 * 1024);
      xout[b * 1024 + jj] = ab;
      outs[(size_t)(b * 59 + t) * 1024 + 512 + jj] = ab;
      __syncthreads();
      if (tid == 0) arrive(&flags[192 + t]);
    }
  }
}

// ---------------- vocab GEMM + exp + row-sum atomics ----------------
template <int USEB>
__global__ __launch_bounds__(512) void k_vocab(
    const u16* __restrict__ A, const u16* __restrict__ WvB,
    const float* __restrict__ WvF, const float* __restrict__ bv,
    float* __restrict__ out, float* __restrict__ rowsum)
{
  const int bid = blockIdx.x;
  const int x = bid & 7, jj = bid >> 3;
  const int mtile = jj % 15, nseq = jj / 15;
  const int ntile = nseq * 8 + x;  // XCD-affine N ordering
  if (ntile >= 196) return;
  const int w = threadIdx.x >> 6, lane = threadIdx.x & 63;
  const int l15 = lane & 15, lhi = lane >> 4;
  const int rbase = mtile * 128 + w * 16;
  const u16* arow = A + (size_t)(rbase + l15) * 1024 + lhi * 8;
  const int cbase = ntile * 256;
  f4 acc[16];
#pragma unroll
  for (int nn = 0; nn < 16; ++nn) acc[nn] = (f4){0.f, 0.f, 0.f, 0.f};
  if constexpr (USEB != 0) {
    const u16* brow = WvB + (size_t)(cbase + l15) * 1024 + lhi * 8;
    for (int k = 0; k < 1024; k += 32) {
      const bf8 a = *(const bf8*)(arow + k);
#pragma unroll
      for (int nn = 0; nn < 16; ++nn)
        acc[nn] = MFMA(a, *(const bf8*)(brow + (size_t)nn * 16384 + k), acc[nn]);
    }
  } else {
    for (int k = 0; k < 1024; k += 32) {
      const bf8 a = *(const bf8*)(arow + k);
#pragma unroll
      for (int nn = 0; nn < 16; ++nn) {
        const int cs = cbase + nn * 16;
        bf8 bfr = {0, 0, 0, 0, 0, 0, 0, 0};
        if (cs < 50000) {
          const float* p = WvF + (size_t)(cs + l15) * 1024 + k + lhi * 8;
          const float4 f0 = *(const float4*)p;
          const float4 f1 = *(const float4*)(p + 4);
          bfr[0] = (short)(__float_as_uint(f0.x) >> 16);
          bfr[1] = (short)(__float_as_uint(f0.y) >> 16);
          bfr[2] = (short)(__float_as_uint(f0.z) >> 16);
          bfr[3] = (short)(__float_as_uint(f0.w) >> 16);
          bfr[4] = (short)(__float_as_uint(f1.x) >> 16);
          bfr[5] = (short)(__float_as_uint(f1.y) >> 16);
          bfr[6] = (short)(__float_as_uint(f1.z) >> 16);
          bfr[7] = (short)(__float_as_uint(f1.w) >> 16);
        }
        acc[nn] = MFMA(a, bfr, acc[nn]);
      }
    }
  }
  float rsv[4] = {0.f, 0.f, 0.f, 0.f};
#pragma unroll
  for (int nn = 0; nn < 16; ++nn) {
    const int cs = cbase + nn * 16;
    if (cs >= 50000) continue;
    const int c = cs + l15;
    const float bb = bv[c];
#pragma unroll
    for (int j = 0; j < 4; ++j) {
      const int r = rbase + lhi * 4 + j;
      if (r < 1888) {
        const float e = __expf(acc[nn][j] + bb);
        out[(size_t)r * 50000 + c] = e;
        rsv[j] += e;
      }
    }
  }
#pragma unroll
  for (int j = 0; j < 4; ++j) {
#pragma unroll
    for (int d = 1; d < 16; d <<= 1) rsv[j] += __shfl_xor(rsv[j], d);
  }
  if (l15 == 0) {
#pragma unroll
    for (int j = 0; j < 4; ++j) {
      const int r = rbase + lhi * 4 + j;
      if (r < 1888) atomicAdd(&rowsum[r], rsv[j]);
    }
  }
}

// ---------------- rowsum -> 1/rowsum ----------------
__global__ void k_invrow(float* rs)
{
  const int i = blockIdx.x * 256 + threadIdx.x;
  if (i < 1920) {
    const float s = rs[i];
    rs[i] = (s > 0.f) ? 1.f / s : 0.f;
  }
}

// ---------------- scale exp values by 1/rowsum ----------------
__global__ __launch_bounds__(256) void k_scale(float* __restrict__ out,
                                               const float* __restrict__ inv)
{
  const int bid = blockIdx.x;
  const int r = bid / 49, ch = bid - r * 49;
  const int c = ch * 1024 + threadIdx.x * 4;
  if (c < 50000) {
    const float s = inv[r];
    float4* p = (float4*)(out + (size_t)r * 50000 + c);
    float4 v = *p;
    v.x *= s; v.y *= s; v.z *= s; v.w *= s;
    *p = v;
  }
}

extern "C" void kernel_launch(void* const* d_in, const int* in_sizes, int n_in,
                              void* d_out, int out_size, void* d_ws, size_t ws_size,
                              hipStream_t stream) {
  const int* posts = (const int*)d_in[0];
  const int* resp = (const int*)d_in[1];
  const float* emb = (const float*)d_in[3];
  const float* aemb = (const float*)d_in[4];
  const float* encWi = (const float*)d_in[5];
  const float* encWh = (const float*)d_in[6];
  const float* enc_bi = (const float*)d_in[7];
  const float* enc_bh = (const float*)d_in[8];
  const float* affWi = (const float*)d_in[9];
  const float* affWh = (const float*)d_in[10];
  const float* aff_bi = (const float*)d_in[11];
  const float* aff_bh = (const float*)d_in[12];
  const float* Wp = (const float*)d_in[13];
  const float* bp = (const float*)d_in[14];
  const float* Wl = (const float*)d_in[15];
  const float* bl = (const float*)d_in[16];
  const float* dWi = (const float*)d_in[17];
  const float* dWh = (const float*)d_in[18];
  const float* dbi = (const float*)d_in[19];
  const float* dbh = (const float*)d_in[20];
  const float* Wa = (const float*)d_in[21];
  const float* Wc = (const float*)d_in[22];
  const float* bc = (const float*)d_in[23];
  const float* Wv = (const float*)d_in[24];
  const float* bv = (const float*)d_in[25];
  char* ws = (char*)d_ws;
  float* out = (float*)d_out;
  const bool useWvB = ws_size >= L::WS_FULL;

  kp_gather<<<4760, 256, 0, stream>>>(posts, resp, emb, aemb, ws);
  kp_wconv<<<19500, 256, 0, stream>>>(encWi, affWi, encWh, affWh, dWi, Wl, Wa, Wp, Wc, ws);
  kp_bcomb<<<6, 256, 0, stream>>>(dWi, bl, dbi, ws);
  if (useWvB) kp_wv<<<50176, 256, 0, stream>>>(Wv, ws);

  // Wcomb = dec_Wi @ Wl  -> f32 [1536][1328]
  k_gemm_nt<<<dim3(96, 6), 256, 0, stream>>>(
      (const u16*)(ws + L::o_decWi), (const u16*)(ws + L::o_WlT),
      (float*)(ws + L::o_Wcomb), nullptr, 1536, 1328, 512);
  kp_pack2<<<11136, 256, 0, stream>>>((const float*)(ws + L::o_Wcomb), dWh, ws);

  // input-gate precomputes
  k_gemm_nt<<<dim3(120, 6), 256, 0, stream>>>(
      (const u16*)(ws + L::o_embP), (const u16*)(ws + L::o_encWi),
      (float*)(ws + L::o_giE), enc_bi, 1920, 1536, 320);
  k_gemm_nt<<<dim3(120, 6), 256, 0, stream>>>(
      (const u16*)(ws + L::o_embA), (const u16*)(ws + L::o_affWi),
      (float*)(ws + L::o_giA), aff_bi, 1920, 1536, 320);
  k_gemm_nt<<<dim3(118, 6), 256, 0, stream>>>(
      (const u16*)(ws + L::o_embD), (const u16*)(ws + L::o_WdE),
      (float*)(ws + L::o_giD), nullptr, 1888, 1536, 320);

  k_persist<<<80, 256, 0, stream>>>(ws, out, bp, enc_bh, aff_bh, dbh, bc);

  if (useWvB)
    k_vocab<1><<<2944, 512, 0, stream>>>(
        (const u16*)(ws + L::o_outsB), (const u16*)(ws + L::o_WvB),
        nullptr, bv, out, (float*)(ws + L::o_rowsum));
  else
    k_vocab<0><<<2944, 512, 0, stream>>>(
        (const u16*)(ws + L::o_outsB), nullptr,
        Wv, bv, out, (float*)(ws + L::o_rowsum));

  k_invrow<<<8, 256, 0, stream>>>((float*)(ws + L::o_rowsum));
  k_scale<<<92512, 256, 0, stream>>>(out, (const float*)(ws + L::o_rowsum));
}